// Round 2
// baseline (18008.716 us; speedup 1.0000x reference)
//
#include <hip/hip_runtime.h>
#include <hip/hip_bf16.h>

typedef unsigned short ushort_t;
typedef __attribute__((ext_vector_type(8))) short bf16x8;
typedef __attribute__((ext_vector_type(4))) float f32x4;
typedef __attribute__((ext_vector_type(2))) float f32x2;

#define B_SZ 32
#define T_SZ 2048
#define I_SZ 512
#define H_SZ 512
#define G_SZ 2048  // 4*H
#define T_C  64    // chunk length
#define N_CHUNK (T_SZ / T_C)
#define NWG_SCAN 16   // 16 WGs x 4 waves = 64 independent waves, 64 flags

__device__ __forceinline__ ushort_t f2bf(float f) {
    union { float f; unsigned u32; } c; c.f = f;
    unsigned r = c.u32 + 0x7fffu + ((c.u32 >> 16) & 1u);
    return (ushort_t)(r >> 16);
}
__device__ __forceinline__ bf16x8 cvt8(const float* __restrict__ p) {
    f32x4 a = *(const f32x4*)p;
    f32x4 b = *(const f32x4*)(p + 4);
    bf16x8 v;
    v[0] = (short)f2bf(a[0]); v[1] = (short)f2bf(a[1]);
    v[2] = (short)f2bf(a[2]); v[3] = (short)f2bf(a[3]);
    v[4] = (short)f2bf(b[0]); v[5] = (short)f2bf(b[1]);
    v[6] = (short)f2bf(b[2]); v[7] = (short)f2bf(b[3]);
    return v;
}
__device__ __forceinline__ float sigf(float x) { return 1.0f / (1.0f + __expf(-x)); }
__device__ __forceinline__ float tanh_fast(float x) {
    float a = fabsf(x);
    float e = __expf(-2.0f * a);
    float t = (1.0f - e) / (1.0f + e);
    return x < 0.0f ? -t : t;
}

// ---------------------------------------------------------------------------
// Phase 1 (per chunk): gx[tc][b][g] = sum_k x[b][t0+tc][k]*Wi[g][k] + bi + bh
// fp32 in, bf16 staged in LDS, MFMA 16x16x32, fp32 out.  (unchanged)
// ---------------------------------------------------------------------------
__global__ __launch_bounds__(256) void gemm_gx(
    const float* __restrict__ X,   // [32][2048][512] fp32
    const float* __restrict__ Wi,  // [2048][512] fp32
    const float* __restrict__ bi,  // [2048] fp32
    const float* __restrict__ bh,  // [2048] fp32
    float* __restrict__ gx,        // [T_C][32][2048] fp32
    int t0)
{
    __shared__ ushort_t As[128][40];
    __shared__ ushort_t Bs[128][40];

    const int tid  = threadIdx.x;
    const int lane = tid & 63;
    const int wv   = tid >> 6;
    const int wm   = (wv >> 1) * 64;
    const int wn   = (wv & 1) * 64;
    const int m0   = blockIdx.y * 128;
    const int n0   = blockIdx.x * 128;

    f32x4 acc[4][4];
#pragma unroll
    for (int i = 0; i < 4; i++)
#pragma unroll
        for (int j = 0; j < 4; j++) acc[i][j] = (f32x4)0.0f;

    const int lrow   = tid >> 2;
    const int lchunk = (tid & 3) * 8;

    const int m1 = m0 + lrow, m2 = m1 + 64;
    const size_t xr1 = ((size_t)(m1 >> 6) * T_SZ + t0 + (m1 & (T_C - 1))) * 512;
    const size_t xr2 = ((size_t)(m2 >> 6) * T_SZ + t0 + (m2 & (T_C - 1))) * 512;

    for (int kk = 0; kk < 512; kk += 32) {
        *(bf16x8*)&As[lrow][lchunk]      = cvt8(X + xr1 + kk + lchunk);
        *(bf16x8*)&As[lrow + 64][lchunk] = cvt8(X + xr2 + kk + lchunk);
        const float* bp = Wi + (size_t)(n0 + lrow) * 512 + kk + lchunk;
        *(bf16x8*)&Bs[lrow][lchunk]      = cvt8(bp);
        *(bf16x8*)&Bs[lrow + 64][lchunk] = cvt8(bp + (size_t)64 * 512);
        __syncthreads();

        const int koff = (lane >> 4) * 8;
        const int rsel = lane & 15;
        bf16x8 af[4], bfr[4];
#pragma unroll
        for (int mt = 0; mt < 4; mt++) af[mt]  = *(const bf16x8*)&As[wm + mt * 16 + rsel][koff];
#pragma unroll
        for (int nt = 0; nt < 4; nt++) bfr[nt] = *(const bf16x8*)&Bs[wn + nt * 16 + rsel][koff];
#pragma unroll
        for (int mt = 0; mt < 4; mt++)
#pragma unroll
            for (int nt = 0; nt < 4; nt++)
                acc[mt][nt] = __builtin_amdgcn_mfma_f32_16x16x32_bf16(af[mt], bfr[nt], acc[mt][nt], 0, 0, 0);
        __syncthreads();
    }

    const int rsel = lane & 15;
    const int rq   = (lane >> 4) * 4;
#pragma unroll
    for (int nt = 0; nt < 4; nt++) {
        const int n = n0 + wn + nt * 16 + rsel;
        const float bias = bi[n] + bh[n];
#pragma unroll
        for (int mt = 0; mt < 4; mt++) {
#pragma unroll
            for (int r = 0; r < 4; r++) {
                const int m  = m0 + wm + mt * 16 + rq + r;
                const int b  = m >> 6;
                const int tc = m & (T_C - 1);
                gx[((size_t)tc * B_SZ + b) * G_SZ + n] = acc[mt][nt][r] + bias;
            }
        }
    }
}

// ---------------------------------------------------------------------------
// Phase 2 (per chunk): persistent scan, 16 WGs x 256 threads = 64 INDEPENDENT
// waves. Wave (w, v): batch-half = v&1, hidden cols [w*32+(v>>1)*16, +16),
// ALL FOUR gates. Wh held as bfrag[4][16] (256 VGPRs, 1 wave/SIMD).
//
// Because each thread now owns i,f,g,o for its fragment positions in
// registers, there is NO LDS exchange and NO __syncthreads anywhere in the
// time loop. Sync is 64 per-WAVE epoch flags (one 128B line each):
//   writer (per wave): 4x relaxed agent 2B h-stores -> lane0 RELEASE store
//     of flag = t+1 (its implicit vmcnt(0) drains the wave's h-stores)
//   reader (per wave): lane l polls flags[l] relaxed until __all(f >= t),
//     then ONE fence(acquire, agent) -> fresh h loads.
// Skew between waves stays <= 1 step: flag >= t+1 implies that wave finished
// READING h(t), so parity buffer (t&1) is safe to overwrite at step t+1.
// gx(t) is prefetched into registers before the poll; out-stores are issued
// after the release, off the critical publish path.
// ---------------------------------------------------------------------------
__global__ __launch_bounds__(256, 1) void lstm_scan(
    const float* __restrict__ Wh,      // [2048][512] fp32
    const float* __restrict__ gx,      // [T_C][32][2048] fp32
    float* __restrict__ out,           // [32][2048][512] ++ hfin[32][512] ++ cfin[32][512]
    ushort_t* __restrict__ hstate,     // [2][32][512] bf16 (parity buffers)
    float*    __restrict__ cstate,     // [32][512] fp32
    unsigned* __restrict__ flags,      // 64 flags, 128B apart: flags[wave*32]
    int t0)
{
    const int w     = blockIdx.x;       // 0..15
    const int tid   = threadIdx.x;
    const int lane  = tid & 63;
    const int v     = tid >> 6;         // wave in WG, 0..3
    const int bhalf = v & 1;            // batch half: 0 -> b 0..15, 1 -> b 16..31
    const int hb    = w * 32 + (v >> 1) * 16;  // hidden base (16 cols)
    const int rsel  = lane & 15;
    const int quad  = lane >> 4;
    const int wvid  = w * 4 + v;        // global wave id 0..63

    // Wh fragments for ALL 4 gates: B-operand, n = rsel, k = quad*8 + kt*32 + j
    bf16x8 bfrag[4][16];
#pragma unroll
    for (int g = 0; g < 4; g++) {
        const float* wp = Wh + (size_t)(g * 512 + hb + rsel) * 512 + quad * 8;
#pragma unroll
        for (int kt = 0; kt < 16; kt++) bfrag[g][kt] = cvt8(wp + kt * 32);
    }

    // This thread's fragment positions: (b = bb + r, h = hb + rsel), r=0..3
    const int bb = bhalf * 16 + quad * 4;
    float c[4] = {0.f, 0.f, 0.f, 0.f};
    float hn[4] = {0.f, 0.f, 0.f, 0.f};
    if (t0 > 0) {
#pragma unroll
        for (int r = 0; r < 4; r++) c[r] = cstate[(size_t)(bb + r) * 512 + hb + rsel];
    }

    for (int tl = 0; tl < T_C; tl++) {
        const int t = t0 + tl;

        // ---- prefetch gx(t) into registers (independent of the flag wait) ----
        float gl[4][4];
        {
            const float* gp = gx + (size_t)tl * (B_SZ * G_SZ) + hb + rsel;
#pragma unroll
            for (int g = 0; g < 4; g++)
#pragma unroll
                for (int r = 0; r < 4; r++)
                    gl[g][r] = gp[(size_t)(bb + r) * G_SZ + g * 512];
        }
        __builtin_amdgcn_sched_barrier(0);   // keep the loads issued before the spin

        // ---- wait: all 64 waves have published h(t) ----
        if (t > 0) {
            const unsigned tgt = (unsigned)t;
            for (;;) {
                unsigned f = __hip_atomic_load(&flags[lane * 32],
                                               __ATOMIC_RELAXED, __HIP_MEMORY_SCOPE_AGENT);
                if (__all((int)(f >= tgt))) break;
            }
            __builtin_amdgcn_fence(__ATOMIC_ACQUIRE, "agent");
        }

        // ---- h(t) @ Wh^T for all 4 gates (4 independent MFMA chains) ----
        f32x4 acc[4];
#pragma unroll
        for (int g = 0; g < 4; g++) acc[g] = (f32x4)0.0f;
        if (t > 0) {
            const ushort_t* hp = hstate + (size_t)(t & 1) * (B_SZ * H_SZ)
                                 + (size_t)(bhalf * 16 + rsel) * 512 + quad * 8;
#pragma unroll
            for (int kt = 0; kt < 16; kt++) {
                bf16x8 a = *(const bf16x8*)(hp + kt * 32);
                acc[0] = __builtin_amdgcn_mfma_f32_16x16x32_bf16(a, bfrag[0][kt], acc[0], 0, 0, 0);
                acc[1] = __builtin_amdgcn_mfma_f32_16x16x32_bf16(a, bfrag[1][kt], acc[1], 0, 0, 0);
                acc[2] = __builtin_amdgcn_mfma_f32_16x16x32_bf16(a, bfrag[2][kt], acc[2], 0, 0, 0);
                acc[3] = __builtin_amdgcn_mfma_f32_16x16x32_bf16(a, bfrag[3][kt], acc[3], 0, 0, 0);
            }
        }

        // ---- gates + state update, all in registers; publish h(t+1) ----
        ushort_t* hw = hstate + (size_t)((t + 1) & 1) * (B_SZ * H_SZ);
#pragma unroll
        for (int r = 0; r < 4; r++) {
            const float ig = acc[0][r] + gl[0][r];
            const float fg = acc[1][r] + gl[1][r];
            const float cg = acc[2][r] + gl[2][r];
            const float og = acc[3][r] + gl[3][r];
            c[r]  = sigf(fg) * c[r] + sigf(ig) * tanh_fast(cg);
            hn[r] = sigf(og) * tanh_fast(c[r]);
            __hip_atomic_store(&hw[(size_t)(bb + r) * 512 + hb + rsel], f2bf(hn[r]),
                               __ATOMIC_RELAXED, __HIP_MEMORY_SCOPE_AGENT);
        }

        // per-wave release: implicit vmcnt(0) covers this wave's h-stores
        if (lane == 0)
            __hip_atomic_store(&flags[wvid * 32], (unsigned)(t + 1),
                               __ATOMIC_RELEASE, __HIP_MEMORY_SCOPE_AGENT);

        // out store AFTER the release (drains during next step's spin)
#pragma unroll
        for (int r = 0; r < 4; r++)
            out[(size_t)(bb + r) * (T_SZ * H_SZ) + (size_t)t * H_SZ + hb + rsel] = hn[r];
    }

    // persist c; finals at end of last chunk (fp32)
#pragma unroll
    for (int r = 0; r < 4; r++) cstate[(size_t)(bb + r) * 512 + hb + rsel] = c[r];
    if (t0 + T_C == T_SZ) {
        float* hf = out + (size_t)B_SZ * T_SZ * H_SZ;
        float* cf = hf + B_SZ * H_SZ;
#pragma unroll
        for (int r = 0; r < 4; r++) {
            hf[(size_t)(bb + r) * 512 + hb + rsel] = hn[r];
            cf[(size_t)(bb + r) * 512 + hb + rsel] = c[r];
        }
    }
}

extern "C" void kernel_launch(void* const* d_in, const int* in_sizes, int n_in,
                              void* d_out, int out_size, void* d_ws, size_t ws_size,
                              hipStream_t stream) {
    const float* x  = (const float*)d_in[0];
    const float* Wi = (const float*)d_in[1];
    const float* bi = (const float*)d_in[2];
    const float* Wh = (const float*)d_in[3];
    const float* bh = (const float*)d_in[4];
    float* out = (float*)d_out;

    const size_t GX_BYTES = (size_t)T_C * B_SZ * G_SZ * sizeof(float);      // 16 MiB
    float*    gxc    = (float*)d_ws;
    ushort_t* hstate = (ushort_t*)((char*)d_ws + GX_BYTES);                 // 64 KiB (2 parity)
    float*    cstate = (float*)   ((char*)d_ws + GX_BYTES + 65536);         // 64 KiB
    unsigned* flags  = (unsigned*)((char*)d_ws + GX_BYTES + 65536 + 65536); // 8 KiB (64 x 128B)

    hipMemsetAsync(flags, 0, 8192, stream);  // epoch flags: zero once per launch

    for (int k = 0; k < N_CHUNK; k++) {
        const int t0 = k * T_C;
        gemm_gx<<<dim3(G_SZ / 128, (B_SZ * T_C) / 128), dim3(256), 0, stream>>>(
            x, Wi, bi, bh, gxc, t0);
        lstm_scan<<<dim3(NWG_SCAN), dim3(256), 0, stream>>>(Wh, gxc, out, hstate, cstate, flags, t0);
    }
}

// Round 4
// 17187.753 us; speedup vs baseline: 1.0478x; 1.0478x over previous
//
#include <hip/hip_runtime.h>
#include <hip/hip_bf16.h>

typedef unsigned short ushort_t;
typedef __attribute__((ext_vector_type(8))) short bf16x8;
typedef __attribute__((ext_vector_type(4))) float f32x4;
typedef __attribute__((ext_vector_type(2))) float f32x2;

#define B_SZ 32
#define T_SZ 2048
#define I_SZ 512
#define H_SZ 512
#define G_SZ 2048  // 4*H
#define T_C  64    // chunk length
#define N_CHUNK (T_SZ / T_C)

__device__ __forceinline__ ushort_t f2bf(float f) {
    union { float f; unsigned u32; } c; c.f = f;
    unsigned r = c.u32 + 0x7fffu + ((c.u32 >> 16) & 1u);
    return (ushort_t)(r >> 16);
}
__device__ __forceinline__ bf16x8 cvt8(const float* __restrict__ p) {
    f32x4 a = *(const f32x4*)p;
    f32x4 b = *(const f32x4*)(p + 4);
    bf16x8 v;
    v[0] = (short)f2bf(a[0]); v[1] = (short)f2bf(a[1]);
    v[2] = (short)f2bf(a[2]); v[3] = (short)f2bf(a[3]);
    v[4] = (short)f2bf(b[0]); v[5] = (short)f2bf(b[1]);
    v[6] = (short)f2bf(b[2]); v[7] = (short)f2bf(b[3]);
    return v;
}
__device__ __forceinline__ float sigf(float x) { return 1.0f / (1.0f + __expf(-x)); }
__device__ __forceinline__ float tanh_fast(float x) {
    float a = fabsf(x);
    float e = __expf(-2.0f * a);
    float t = (1.0f - e) / (1.0f + e);
    return x < 0.0f ? -t : t;
}

// ---------------------------------------------------------------------------
// Phase 1 (per chunk): gx[tc][b][g] = sum_k x[b][t0+tc][k]*Wi[g][k] + bi + bh
// fp32 in, bf16 staged in LDS, MFMA 16x16x32, fp32 out.  (unchanged)
// ---------------------------------------------------------------------------
__global__ __launch_bounds__(256) void gemm_gx(
    const float* __restrict__ X,   // [32][2048][512] fp32
    const float* __restrict__ Wi,  // [2048][512] fp32
    const float* __restrict__ bi,  // [2048] fp32
    const float* __restrict__ bh,  // [2048] fp32
    float* __restrict__ gx,        // [T_C][32][2048] fp32
    int t0)
{
    __shared__ ushort_t As[128][40];
    __shared__ ushort_t Bs[128][40];

    const int tid  = threadIdx.x;
    const int lane = tid & 63;
    const int wv   = tid >> 6;
    const int wm   = (wv >> 1) * 64;
    const int wn   = (wv & 1) * 64;
    const int m0   = blockIdx.y * 128;
    const int n0   = blockIdx.x * 128;

    f32x4 acc[4][4];
#pragma unroll
    for (int i = 0; i < 4; i++)
#pragma unroll
        for (int j = 0; j < 4; j++) acc[i][j] = (f32x4)0.0f;

    const int lrow   = tid >> 2;
    const int lchunk = (tid & 3) * 8;

    const int m1 = m0 + lrow, m2 = m1 + 64;
    const size_t xr1 = ((size_t)(m1 >> 6) * T_SZ + t0 + (m1 & (T_C - 1))) * 512;
    const size_t xr2 = ((size_t)(m2 >> 6) * T_SZ + t0 + (m2 & (T_C - 1))) * 512;

    for (int kk = 0; kk < 512; kk += 32) {
        *(bf16x8*)&As[lrow][lchunk]      = cvt8(X + xr1 + kk + lchunk);
        *(bf16x8*)&As[lrow + 64][lchunk] = cvt8(X + xr2 + kk + lchunk);
        const float* bp = Wi + (size_t)(n0 + lrow) * 512 + kk + lchunk;
        *(bf16x8*)&Bs[lrow][lchunk]      = cvt8(bp);
        *(bf16x8*)&Bs[lrow + 64][lchunk] = cvt8(bp + (size_t)64 * 512);
        __syncthreads();

        const int koff = (lane >> 4) * 8;
        const int rsel = lane & 15;
        bf16x8 af[4], bfr[4];
#pragma unroll
        for (int mt = 0; mt < 4; mt++) af[mt]  = *(const bf16x8*)&As[wm + mt * 16 + rsel][koff];
#pragma unroll
        for (int nt = 0; nt < 4; nt++) bfr[nt] = *(const bf16x8*)&Bs[wn + nt * 16 + rsel][koff];
#pragma unroll
        for (int mt = 0; mt < 4; mt++)
#pragma unroll
            for (int nt = 0; nt < 4; nt++)
                acc[mt][nt] = __builtin_amdgcn_mfma_f32_16x16x32_bf16(af[mt], bfr[nt], acc[mt][nt], 0, 0, 0);
        __syncthreads();
    }

    const int rsel = lane & 15;
    const int rq   = (lane >> 4) * 4;
#pragma unroll
    for (int nt = 0; nt < 4; nt++) {
        const int n = n0 + wn + nt * 16 + rsel;
        const float bias = bi[n] + bh[n];
#pragma unroll
        for (int mt = 0; mt < 4; mt++) {
#pragma unroll
            for (int r = 0; r < 4; r++) {
                const int m  = m0 + wm + mt * 16 + rq + r;
                const int b  = m >> 6;
                const int tc = m & (T_C - 1);
                gx[((size_t)tc * B_SZ + b) * G_SZ + n] = acc[mt][nt][r] + bias;
            }
        }
    }
}

// ---------------------------------------------------------------------------
// Phase 2 (per chunk): persistent scan, 32 WGs x 256 threads. WG w owns hidden
// [16w,16w+16); wave g owns gate g for the MFMA. Round-1 sync skeleton kept
// verbatim (32 per-WG flags at same offsets, tid0 release, poll+acquire
// fence, parity h buffers, SAME workspace footprint).
//
// Change vs round 1: barrier #2 is removed by restructuring the combine:
//  - gs is parity double-buffered (gs2[t&1]) and stays in the MFMA
//    accumulator layout (f32x4 tiles) -> 2x ds_write_b128 per wave.
//  - after the single __syncthreads, ALL 4 waves redundantly read all 4
//    gates for the SAME 8 (b,h) positions (acc layout) and compute
//    identical c/h. Redundant VALU is free (VALUBusy < 1%).
//  - wave 0 alone stores the WG's full h tile (relaxed agent 2B stores);
//    tid0's RELEASE (implicit wave-0 vmcnt(0)) drains exactly those.
// Safety (same invariant as round 1): flag = t+1 is published after
// barrier#1(t); each wave's pre-barrier s_waitcnt vmcnt(0) drained its h(t)
// loads, so flag>=t+1 still implies all local reads of parity buffer t&1
// are done before any remote overwrite at step t+1. gs parity removes the
// gs(t+1)-write vs combine(t)-read race that the single barrier can't order.
// ---------------------------------------------------------------------------
__global__ __launch_bounds__(256) void lstm_scan(
    const float* __restrict__ Wh,      // [2048][512] fp32
    const float* __restrict__ gx,      // [T_C][32][2048] fp32
    float* __restrict__ out,           // [32][2048][512] ++ hfin[32][512] ++ cfin[32][512]
    ushort_t* __restrict__ hstate,     // [2][32][512] bf16 (parity buffers)
    float*    __restrict__ cstate,     // [32][512] fp32
    unsigned* __restrict__ flags,      // 32 flags, 128B apart: flags[w*32]
    int t0)
{
    const int w    = blockIdx.x;
    const int hb   = w * 16;
    const int tid  = threadIdx.x;
    const int lane = tid & 63;
    const int g    = tid >> 6;
    const int rsel = lane & 15;
    const int quad = lane >> 4;

    // [parity][gate][b/4][rsel] of f32x4 (r=0..3) = 16 KiB
    __shared__ f32x4 gs2[2][4][8][16];

    // persistent Wh fragments (bf16): B-operand, n = lane&15, k = quad*8 + kt*32 + j
    bf16x8 bfrag[16];
    {
        const float* wp = Wh + (size_t)(g * 512 + hb + rsel) * 512 + quad * 8;
#pragma unroll
        for (int kt = 0; kt < 16; kt++) bfrag[kt] = cvt8(wp + kt * 32);
    }

    // this thread's 8 combine positions: b = quad*4 + r + 16*half, h = hb+rsel
    float c[2][4], hn[2][4];
#pragma unroll
    for (int hf = 0; hf < 2; hf++)
#pragma unroll
        for (int r = 0; r < 4; r++) { c[hf][r] = 0.0f; hn[hf][r] = 0.0f; }
    if (t0 > 0) {
#pragma unroll
        for (int hf = 0; hf < 2; hf++)
#pragma unroll
            for (int r = 0; r < 4; r++)
                c[hf][r] = cstate[(size_t)(quad * 4 + r + 16 * hf) * 512 + hb + rsel];
    }

    for (int tl = 0; tl < T_C; tl++) {
        const int t = t0 + tl;
        const int p = t & 1;

        // ---- prefetch gx(t) into registers (independent of the flag wait) ----
        float gl0[4], gl1[4];
        {
            const float* gp = gx + (size_t)tl * (B_SZ * G_SZ) + (size_t)(g * 512 + hb + rsel);
#pragma unroll
            for (int r = 0; r < 4; r++) {
                const int b0 = quad * 4 + r;
                gl0[r] = gp[(size_t)b0 * G_SZ];
                gl1[r] = gp[(size_t)(b0 + 16) * G_SZ];
            }
        }
        __builtin_amdgcn_sched_barrier(0);   // keep the loads issued before the spin

        // ---- wait: all 32 WGs have published h(t) (round-1 verbatim) ----
        if (t > 0) {
            const unsigned tgt = (unsigned)t;
            for (;;) {
                unsigned f = __hip_atomic_load(&flags[(lane & 31) * 32],
                                               __ATOMIC_RELAXED, __HIP_MEMORY_SCOPE_AGENT);
                if (__all((int)(f >= tgt))) break;
            }
            __builtin_amdgcn_fence(__ATOMIC_ACQUIRE, "agent");
        }

        // ---- h(t) @ Wh^T : 4 independent MFMA chains (round-1 verbatim) ----
        f32x4 acc0a = (f32x4)0.0f, acc0b = (f32x4)0.0f;
        f32x4 acc1a = (f32x4)0.0f, acc1b = (f32x4)0.0f;
        if (t > 0) {
            const ushort_t* hp = hstate + (size_t)p * (B_SZ * H_SZ)
                                 + (size_t)rsel * 512 + quad * 8;
#pragma unroll
            for (int kt = 0; kt < 16; kt += 2) {
                bf16x8 a0 = *(const bf16x8*)(hp + kt * 32);
                bf16x8 a1 = *(const bf16x8*)(hp + (size_t)16 * 512 + kt * 32);
                bf16x8 a2 = *(const bf16x8*)(hp + (kt + 1) * 32);
                bf16x8 a3 = *(const bf16x8*)(hp + (size_t)16 * 512 + (kt + 1) * 32);
                acc0a = __builtin_amdgcn_mfma_f32_16x16x32_bf16(a0, bfrag[kt],     acc0a, 0, 0, 0);
                acc1a = __builtin_amdgcn_mfma_f32_16x16x32_bf16(a1, bfrag[kt],     acc1a, 0, 0, 0);
                acc0b = __builtin_amdgcn_mfma_f32_16x16x32_bf16(a2, bfrag[kt + 1], acc0b, 0, 0, 0);
                acc1b = __builtin_amdgcn_mfma_f32_16x16x32_bf16(a3, bfrag[kt + 1], acc1b, 0, 0, 0);
            }
        }
        const f32x4 acc0 = acc0a + acc0b;
        const f32x4 acc1 = acc1a + acc1b;

        // ---- gate exchange in acc layout: 2x ds_write_b128 into parity gs ----
        {
            f32x4 w0, w1;
#pragma unroll
            for (int r = 0; r < 4; r++) { w0[r] = acc0[r] + gl0[r]; w1[r] = acc1[r] + gl1[r]; }
            gs2[p][g][quad][rsel]     = w0;   // batches quad*4..+3
            gs2[p][g][quad + 4][rsel] = w1;   // batches 16+quad*4..+3
        }
        __syncthreads();   // the ONLY barrier (its waitcnt also drains h(t) loads)

        // ---- redundant combine (all 4 waves, identical results) ----
#pragma unroll
        for (int hf = 0; hf < 2; hf++) {
            const f32x4 vi = gs2[p][0][quad + 4 * hf][rsel];
            const f32x4 vf = gs2[p][1][quad + 4 * hf][rsel];
            const f32x4 vc = gs2[p][2][quad + 4 * hf][rsel];
            const f32x4 vo = gs2[p][3][quad + 4 * hf][rsel];
#pragma unroll
            for (int r = 0; r < 4; r++) {
                c[hf][r]  = sigf(vf[r]) * c[hf][r] + sigf(vi[r]) * tanh_fast(vc[r]);
                hn[hf][r] = sigf(vo[r]) * tanh_fast(c[hf][r]);
            }
        }

        // ---- wave 0 publishes the WG's whole h(t+1) tile ----
        if (g == 0) {
            ushort_t* hw = hstate + (size_t)((t + 1) & 1) * (B_SZ * H_SZ);
#pragma unroll
            for (int hf = 0; hf < 2; hf++)
#pragma unroll
                for (int r = 0; r < 4; r++)
                    __hip_atomic_store(&hw[(size_t)(quad * 4 + r + 16 * hf) * 512 + hb + rsel],
                                       f2bf(hn[hf][r]),
                                       __ATOMIC_RELAXED, __HIP_MEMORY_SCOPE_AGENT);
        }

        // release: tid0 (wave 0) — implicit vmcnt(0) drains wave-0's h-stores
        if (tid == 0)
            __hip_atomic_store(&flags[w * 32], (unsigned)(t + 1),
                               __ATOMIC_RELEASE, __HIP_MEMORY_SCOPE_AGENT);

        // out stores AFTER the release (wave 0 owns the tile), off critical path
        if (g == 0) {
#pragma unroll
            for (int hf = 0; hf < 2; hf++)
#pragma unroll
                for (int r = 0; r < 4; r++)
                    out[(size_t)(quad * 4 + r + 16 * hf) * (T_SZ * H_SZ)
                        + (size_t)t * H_SZ + hb + rsel] = hn[hf][r];
        }
    }

    // persist c; finals at end of last chunk (wave 0 holds identical copies)
    if (g == 0) {
#pragma unroll
        for (int hf = 0; hf < 2; hf++)
#pragma unroll
            for (int r = 0; r < 4; r++)
                cstate[(size_t)(quad * 4 + r + 16 * hf) * 512 + hb + rsel] = c[hf][r];
        if (t0 + T_C == T_SZ) {
            float* hf_ = out + (size_t)B_SZ * T_SZ * H_SZ;
            float* cf_ = hf_ + B_SZ * H_SZ;
#pragma unroll
            for (int hf = 0; hf < 2; hf++)
#pragma unroll
                for (int r = 0; r < 4; r++) {
                    const size_t idx = (size_t)(quad * 4 + r + 16 * hf) * 512 + hb + rsel;
                    hf_[idx] = hn[hf][r];
                    cf_[idx] = c[hf][r];
                }
        }
    }
}

extern "C" void kernel_launch(void* const* d_in, const int* in_sizes, int n_in,
                              void* d_out, int out_size, void* d_ws, size_t ws_size,
                              hipStream_t stream) {
    const float* x  = (const float*)d_in[0];
    const float* Wi = (const float*)d_in[1];
    const float* bi = (const float*)d_in[2];
    const float* Wh = (const float*)d_in[3];
    const float* bh = (const float*)d_in[4];
    float* out = (float*)d_out;

    const size_t GX_BYTES = (size_t)T_C * B_SZ * G_SZ * sizeof(float);      // 16 MiB
    float*    gxc    = (float*)d_ws;
    ushort_t* hstate = (ushort_t*)((char*)d_ws + GX_BYTES);                 // 64 KiB (2 parity)
    float*    cstate = (float*)   ((char*)d_ws + GX_BYTES + 65536);         // 64 KiB
    unsigned* flags  = (unsigned*)((char*)d_ws + GX_BYTES + 65536 + 65536); // 8 KiB (round-1 footprint)

    hipMemsetAsync(flags, 0, 8192, stream);  // epoch flags: zero once per launch

    for (int k = 0; k < N_CHUNK; k++) {
        const int t0 = k * T_C;
        gemm_gx<<<dim3(G_SZ / 128, (B_SZ * T_C) / 128), dim3(256), 0, stream>>>(
            x, Wi, bi, bh, gxc, t0);
        lstm_scan<<<dim3(32), dim3(256), 0, stream>>>(Wh, gxc, out, hstate, cstate, flags, t0);
    }
}

// Round 5
// 14085.472 us; speedup vs baseline: 1.2785x; 1.2202x over previous
//
#include <hip/hip_runtime.h>
#include <hip/hip_bf16.h>

typedef unsigned short ushort_t;
typedef __attribute__((ext_vector_type(8))) short bf16x8;
typedef __attribute__((ext_vector_type(4))) float f32x4;
typedef __attribute__((ext_vector_type(2))) float f32x2;

#define B_SZ 32
#define T_SZ 2048
#define I_SZ 512
#define H_SZ 512
#define G_SZ 2048  // 4*H
#define T_C  64    // chunk length
#define N_CHUNK (T_SZ / T_C)

__device__ __forceinline__ ushort_t f2bf(float f) {
    union { float f; unsigned u32; } c; c.f = f;
    unsigned r = c.u32 + 0x7fffu + ((c.u32 >> 16) & 1u);
    return (ushort_t)(r >> 16);
}
__device__ __forceinline__ bf16x8 cvt8(const float* __restrict__ p) {
    f32x4 a = *(const f32x4*)p;
    f32x4 b = *(const f32x4*)(p + 4);
    bf16x8 v;
    v[0] = (short)f2bf(a[0]); v[1] = (short)f2bf(a[1]);
    v[2] = (short)f2bf(a[2]); v[3] = (short)f2bf(a[3]);
    v[4] = (short)f2bf(b[0]); v[5] = (short)f2bf(b[1]);
    v[6] = (short)f2bf(b[2]); v[7] = (short)f2bf(b[3]);
    return v;
}
__device__ __forceinline__ float sigf(float x) { return 1.0f / (1.0f + __expf(-x)); }
__device__ __forceinline__ float tanh_fast(float x) {
    float a = fabsf(x);
    float e = __expf(-2.0f * a);
    float t = (1.0f - e) / (1.0f + e);
    return x < 0.0f ? -t : t;
}

// ---------------------------------------------------------------------------
// Phase 1 (per chunk): gx[tc][b][g] = sum_k x[b][t0+tc][k]*Wi[g][k] + bi + bh
// fp32 in, bf16 staged in LDS, MFMA 16x16x32, fp32 out.  (unchanged)
// ---------------------------------------------------------------------------
__global__ __launch_bounds__(256) void gemm_gx(
    const float* __restrict__ X,   // [32][2048][512] fp32
    const float* __restrict__ Wi,  // [2048][512] fp32
    const float* __restrict__ bi,  // [2048] fp32
    const float* __restrict__ bh,  // [2048] fp32
    float* __restrict__ gx,        // [T_C][32][2048] fp32
    int t0)
{
    __shared__ ushort_t As[128][40];
    __shared__ ushort_t Bs[128][40];

    const int tid  = threadIdx.x;
    const int lane = tid & 63;
    const int wv   = tid >> 6;
    const int wm   = (wv >> 1) * 64;
    const int wn   = (wv & 1) * 64;
    const int m0   = blockIdx.y * 128;
    const int n0   = blockIdx.x * 128;

    f32x4 acc[4][4];
#pragma unroll
    for (int i = 0; i < 4; i++)
#pragma unroll
        for (int j = 0; j < 4; j++) acc[i][j] = (f32x4)0.0f;

    const int lrow   = tid >> 2;
    const int lchunk = (tid & 3) * 8;

    const int m1 = m0 + lrow, m2 = m1 + 64;
    const size_t xr1 = ((size_t)(m1 >> 6) * T_SZ + t0 + (m1 & (T_C - 1))) * 512;
    const size_t xr2 = ((size_t)(m2 >> 6) * T_SZ + t0 + (m2 & (T_C - 1))) * 512;

    for (int kk = 0; kk < 512; kk += 32) {
        *(bf16x8*)&As[lrow][lchunk]      = cvt8(X + xr1 + kk + lchunk);
        *(bf16x8*)&As[lrow + 64][lchunk] = cvt8(X + xr2 + kk + lchunk);
        const float* bp = Wi + (size_t)(n0 + lrow) * 512 + kk + lchunk;
        *(bf16x8*)&Bs[lrow][lchunk]      = cvt8(bp);
        *(bf16x8*)&Bs[lrow + 64][lchunk] = cvt8(bp + (size_t)64 * 512);
        __syncthreads();

        const int koff = (lane >> 4) * 8;
        const int rsel = lane & 15;
        bf16x8 af[4], bfr[4];
#pragma unroll
        for (int mt = 0; mt < 4; mt++) af[mt]  = *(const bf16x8*)&As[wm + mt * 16 + rsel][koff];
#pragma unroll
        for (int nt = 0; nt < 4; nt++) bfr[nt] = *(const bf16x8*)&Bs[wn + nt * 16 + rsel][koff];
#pragma unroll
        for (int mt = 0; mt < 4; mt++)
#pragma unroll
            for (int nt = 0; nt < 4; nt++)
                acc[mt][nt] = __builtin_amdgcn_mfma_f32_16x16x32_bf16(af[mt], bfr[nt], acc[mt][nt], 0, 0, 0);
        __syncthreads();
    }

    const int rsel = lane & 15;
    const int rq   = (lane >> 4) * 4;
#pragma unroll
    for (int nt = 0; nt < 4; nt++) {
        const int n = n0 + wn + nt * 16 + rsel;
        const float bias = bi[n] + bh[n];
#pragma unroll
        for (int mt = 0; mt < 4; mt++) {
#pragma unroll
            for (int r = 0; r < 4; r++) {
                const int m  = m0 + wm + mt * 16 + rq + r;
                const int b  = m >> 6;
                const int tc = m & (T_C - 1);
                gx[((size_t)tc * B_SZ + b) * G_SZ + n] = acc[mt][nt][r] + bias;
            }
        }
    }
}

// ---------------------------------------------------------------------------
// Phase 2 (per chunk): persistent scan, 32 WGs x 256 threads. WG w owns hidden
// [16w,16w+16); wave g owns gate g. EXACT round-1 structure (verified 422us:
// 32 per-WG flags, two barriers, parity h buffers, 108 VGPR) + two targeted
// fixes for the hidden fabric costs:
//
//  (1) LDS-RELAYED POLL: only wave 3 polls the 32 fabric flag lines; waves
//      0-2 spin on an LDS epoch word and then execute the same acquire
//      fence. Cuts the coherent-load storm on the flag lines 4x (128 -> 32
//      polling waves chip-wide), so the producers' release stores win LLC
//      arbitration sooner.
//  (2) WRITE-THROUGH 'out': the per-step out store is an 8B agent-scope
//      relaxed atomic store -> no dirty L2 lines for the 32 per-step
//      releases to write back.
// ---------------------------------------------------------------------------
__global__ __launch_bounds__(256) void lstm_scan(
    const float* __restrict__ Wh,      // [2048][512] fp32
    const float* __restrict__ gx,      // [T_C][32][2048] fp32
    float* __restrict__ out,           // [32][2048][512] ++ hfin[32][512] ++ cfin[32][512]
    ushort_t* __restrict__ hstate,     // [2][32][512] bf16 (parity buffers)
    float*    __restrict__ cstate,     // [32][512] fp32
    unsigned* __restrict__ flags,      // 32 flags, 128B apart: flags[w*32]
    int t0)
{
    const int w    = blockIdx.x;
    const int hb   = w * 16;
    const int tid  = threadIdx.x;
    const int lane = tid & 63;
    const int g    = tid >> 6;
    const int rsel = lane & 15;
    const int quad = lane >> 4;

    __shared__ float gs[4][32][16];    // [gate][batch][hidden]
    __shared__ unsigned eflag;         // LDS epoch relay (wave 3 -> waves 0-2)

    if (tid == 0) eflag = 0;

    // persistent Wh fragments (bf16): B-operand, n = lane&15, k = quad*8 + kt*32 + j
    bf16x8 bfrag[16];
    {
        const float* wp = Wh + (size_t)(g * 512 + hb + rsel) * 512 + quad * 8;
#pragma unroll
        for (int kt = 0; kt < 16; kt++) bfrag[kt] = cvt8(wp + kt * 32);
    }

    const int eb = tid >> 3;           // batch 0..31
    const int eh = (tid & 7) * 2;      // hidden pair
    const size_t cidx = (size_t)eb * 512 + hb + eh;
    float c0 = 0.0f, c1 = 0.0f;
    if (t0 > 0) { c0 = cstate[cidx]; c1 = cstate[cidx + 1]; }
    float h0 = 0.0f, h1 = 0.0f;
    const size_t out_base = (size_t)eb * (T_SZ * H_SZ) + hb + eh;

    __syncthreads();   // eflag init visible before anyone spins on it

    for (int tl = 0; tl < T_C; tl++) {
        const int t = t0 + tl;

        // ---- prefetch gx(t) into registers (independent of the flag wait) ----
        float gl0[4], gl1[4];
        {
            const float* gp = gx + (size_t)tl * (B_SZ * G_SZ) + (size_t)(g * 512 + hb + rsel);
#pragma unroll
            for (int r = 0; r < 4; r++) {
                const int b0 = quad * 4 + r;
                gl0[r] = gp[(size_t)b0 * G_SZ];
                gl1[r] = gp[(size_t)(b0 + 16) * G_SZ];
            }
        }
        __builtin_amdgcn_sched_barrier(0);   // keep the loads issued before the spin

        // ---- wait: all 32 WGs have published h(t) ----
        if (t > 0) {
            const unsigned tgt = (unsigned)t;
            if (g == 3) {
                // wave 3 polls the fabric flags (2 lanes per flag)
                for (;;) {
                    unsigned f = __hip_atomic_load(&flags[(lane & 31) * 32],
                                                   __ATOMIC_RELAXED, __HIP_MEMORY_SCOPE_AGENT);
                    if (__all((int)(f >= tgt))) break;
                }
                __builtin_amdgcn_sched_barrier(0);   // keep relay after the poll
                __hip_atomic_store(&eflag, tgt, __ATOMIC_RELAXED,
                                   __HIP_MEMORY_SCOPE_WORKGROUP);
            } else {
                // waves 0-2 spin locally on LDS (no fabric traffic)
                while (__hip_atomic_load(&eflag, __ATOMIC_RELAXED,
                                         __HIP_MEMORY_SCOPE_WORKGROUP) < tgt) {}
            }
            __builtin_amdgcn_fence(__ATOMIC_ACQUIRE, "agent");
        }

        // ---- h(t) @ Wh^T : 4 independent MFMA chains for ILP ----
        f32x4 acc0a = (f32x4)0.0f, acc0b = (f32x4)0.0f;
        f32x4 acc1a = (f32x4)0.0f, acc1b = (f32x4)0.0f;
        if (t > 0) {
            const ushort_t* hp = hstate + (size_t)(t & 1) * (B_SZ * H_SZ)
                                 + (size_t)rsel * 512 + quad * 8;
#pragma unroll
            for (int kt = 0; kt < 16; kt += 2) {
                bf16x8 a0 = *(const bf16x8*)(hp + kt * 32);
                bf16x8 a1 = *(const bf16x8*)(hp + (size_t)16 * 512 + kt * 32);
                bf16x8 a2 = *(const bf16x8*)(hp + (kt + 1) * 32);
                bf16x8 a3 = *(const bf16x8*)(hp + (size_t)16 * 512 + (kt + 1) * 32);
                acc0a = __builtin_amdgcn_mfma_f32_16x16x32_bf16(a0, bfrag[kt],     acc0a, 0, 0, 0);
                acc1a = __builtin_amdgcn_mfma_f32_16x16x32_bf16(a1, bfrag[kt],     acc1a, 0, 0, 0);
                acc0b = __builtin_amdgcn_mfma_f32_16x16x32_bf16(a2, bfrag[kt + 1], acc0b, 0, 0, 0);
                acc1b = __builtin_amdgcn_mfma_f32_16x16x32_bf16(a3, bfrag[kt + 1], acc1b, 0, 0, 0);
            }
        }
        const f32x4 acc0 = acc0a + acc0b;
        const f32x4 acc1 = acc1a + acc1b;

        // C/D layout: col = lane&15 (hidden), row = quad*4 + r (batch)
#pragma unroll
        for (int r = 0; r < 4; r++) {
            const int b0 = quad * 4 + r;
            gs[g][b0][rsel]      = acc0[r] + gl0[r];
            gs[g][b0 + 16][rsel] = acc1[r] + gl1[r];
        }
        __syncthreads();

        // ---- elementwise gates + state update ----
        {
            const float ig0 = gs[0][eb][eh], ig1 = gs[0][eb][eh + 1];
            const float fg0 = gs[1][eb][eh], fg1 = gs[1][eb][eh + 1];
            const float cg0 = gs[2][eb][eh], cg1 = gs[2][eb][eh + 1];
            const float og0 = gs[3][eb][eh], og1 = gs[3][eb][eh + 1];
            c0 = sigf(fg0) * c0 + sigf(ig0) * tanh_fast(cg0);
            c1 = sigf(fg1) * c1 + sigf(ig1) * tanh_fast(cg1);
            h0 = sigf(og0) * tanh_fast(c0);
            h1 = sigf(og1) * tanh_fast(c1);
            // publish h(t+1) into parity buffer (t+1)&1
            const unsigned hpack = (unsigned)f2bf(h0) | ((unsigned)f2bf(h1) << 16);
            ushort_t* wrp = hstate + (size_t)((t + 1) & 1) * (B_SZ * H_SZ) + cidx;
            __hip_atomic_store((unsigned*)wrp, hpack, __ATOMIC_RELAXED, __HIP_MEMORY_SCOPE_AGENT);
        }
        __syncthreads();  // all lanes' h stores drained before flag release

        if (tid == 0)
            __hip_atomic_store(&flags[w * 32], (unsigned)(t + 1),
                               __ATOMIC_RELEASE, __HIP_MEMORY_SCOPE_AGENT);

        // out store AFTER the release; write-through (no dirty L2 on release path)
        {
            union { unsigned long long u; f32x2 v; } uo;
            uo.v[0] = h0; uo.v[1] = h1;
            __hip_atomic_store((unsigned long long*)(out + out_base + (size_t)t * H_SZ),
                               uo.u, __ATOMIC_RELAXED, __HIP_MEMORY_SCOPE_AGENT);
        }
    }

    // persist c; finals at end of last chunk (fp32)
    cstate[cidx] = c0; cstate[cidx + 1] = c1;
    if (t0 + T_C == T_SZ) {
        float* hf = out + (size_t)B_SZ * T_SZ * H_SZ;
        f32x2 hv; hv[0] = h0; hv[1] = h1;
        *(f32x2*)(hf + cidx) = hv;
        float* cf = hf + B_SZ * H_SZ;
        f32x2 cv; cv[0] = c0; cv[1] = c1;
        *(f32x2*)(cf + cidx) = cv;
    }
}

extern "C" void kernel_launch(void* const* d_in, const int* in_sizes, int n_in,
                              void* d_out, int out_size, void* d_ws, size_t ws_size,
                              hipStream_t stream) {
    const float* x  = (const float*)d_in[0];
    const float* Wi = (const float*)d_in[1];
    const float* bi = (const float*)d_in[2];
    const float* Wh = (const float*)d_in[3];
    const float* bh = (const float*)d_in[4];
    float* out = (float*)d_out;

    const size_t GX_BYTES = (size_t)T_C * B_SZ * G_SZ * sizeof(float);      // 16 MiB
    float*    gxc    = (float*)d_ws;
    ushort_t* hstate = (ushort_t*)((char*)d_ws + GX_BYTES);                 // 64 KiB (2 parity)
    float*    cstate = (float*)   ((char*)d_ws + GX_BYTES + 65536);         // 64 KiB
    unsigned* flags  = (unsigned*)((char*)d_ws + GX_BYTES + 65536 + 65536); // 8 KiB (32 x 128B)

    hipMemsetAsync(flags, 0, 8192, stream);  // epoch flags: zero once per launch

    for (int k = 0; k < N_CHUNK; k++) {
        const int t0 = k * T_C;
        gemm_gx<<<dim3(G_SZ / 128, (B_SZ * T_C) / 128), dim3(256), 0, stream>>>(
            x, Wi, bi, bh, gxc, t0);
        lstm_scan<<<dim3(32), dim3(256), 0, stream>>>(Wh, gxc, out, hstate, cstate, flags, t0);
    }
}